// Round 6
// baseline (135.392 us; speedup 1.0000x reference)
//
#include <hip/hip_runtime.h>

static constexpr int Vn = 1024;   // codebook size
static constexpr int Dn = 256;    // code dim
static constexpr int NT = 65536;  // B * TOK

typedef float vfloat4 __attribute__((ext_vector_type(4)));  // native vec for stores

// ---------------------------------------------------------------------------
// Kernel 1: G = W * W^T (1024x1024, K=256), fp32. VERBATIM round-4 (best
// measured): 64x32 tiles, 512 blocks = 2 blocks/CU, reg-prefetched staging,
// nt G stores. fmaf chain k=0..255 ascending -> bit-identical G/norms.
// ---------------------------------------------------------------------------
__global__ __launch_bounds__(256) void gram_kernel(const float* __restrict__ W,
                                                   float* __restrict__ G,
                                                   float* __restrict__ norms) {
    __shared__ float As[32][68];   // [k-in-chunk][m 0..63], 16B-aligned rows
    __shared__ float Bs[32][36];   // [k-in-chunk][n 0..31], 144B rows
    const int tid = threadIdx.x;
    const int tx = tid & 7;        // 0..7  -> 4 consecutive cols
    const int ty = tid >> 3;       // 0..31 -> 2 consecutive rows
    const int bm = blockIdx.y * 64;
    const int bn = blockIdx.x * 32;
    const float4* Wv = (const float4*)W;   // [1024][64] float4

    const int m0  = tid >> 3;      // 0..31
    const int kql = tid & 7;       // f4 within the 32-k chunk

    float4 pa[2], pb;
#pragma unroll
    for (int s = 0; s < 2; ++s)
        pa[s] = Wv[(bm + m0 + 32 * s) * 64 + kql];
    pb = Wv[(bn + m0) * 64 + kql];

    float acc[2][4] = {};
    for (int c = 0; c < 8; ++c) {
#pragma unroll
        for (int s = 0; s < 2; ++s) {
            const int m = m0 + 32 * s;
            As[kql * 4 + 0][m] = pa[s].x;
            As[kql * 4 + 1][m] = pa[s].y;
            As[kql * 4 + 2][m] = pa[s].z;
            As[kql * 4 + 3][m] = pa[s].w;
        }
        Bs[kql * 4 + 0][m0] = pb.x;
        Bs[kql * 4 + 1][m0] = pb.y;
        Bs[kql * 4 + 2][m0] = pb.z;
        Bs[kql * 4 + 3][m0] = pb.w;
        __syncthreads();
        if (c < 7) {
            const int kq = (c + 1) * 8 + kql;
#pragma unroll
            for (int s = 0; s < 2; ++s)
                pa[s] = Wv[(bm + m0 + 32 * s) * 64 + kq];
            pb = Wv[(bn + m0) * 64 + kq];
        }
        const float* Ab = &As[0][ty * 2];
        const float* Bb = &Bs[0][tx * 4];
        float2 a_c = *(const float2*)Ab;
        float4 b_c = *(const float4*)Bb;
#pragma unroll
        for (int kk = 0; kk < 32; ++kk) {
            const int kn = (kk < 31) ? kk + 1 : kk;
            const float2 a_n = *(const float2*)(Ab + kn * 68);
            const float4 b_n = *(const float4*)(Bb + kn * 36);
            const float a_s[2] = {a_c.x, a_c.y};
            const float b_s[4] = {b_c.x, b_c.y, b_c.z, b_c.w};
#pragma unroll
            for (int u = 0; u < 2; ++u)
#pragma unroll
                for (int w = 0; w < 4; ++w)
                    acc[u][w] = fmaf(a_s[u], b_s[w], acc[u][w]);  // k ascending
            a_c = a_n;
            b_c = b_n;
        }
        __syncthreads();
    }
#pragma unroll
    for (int u = 0; u < 2; ++u) {
        const int row = bm + ty * 2 + u;
        vfloat4 o;
        o.x = acc[u][0]; o.y = acc[u][1]; o.z = acc[u][2]; o.w = acc[u][3];
        __builtin_nontemporal_store(o, (vfloat4*)(G + row * Vn + bn + tx * 4));
        const int cd = row - (bn + tx * 4);
        if (cd >= 0 && cd < 4) norms[row] = acc[u][cd];
    }
}

// ---------------------------------------------------------------------------
// Kernel 2 (FUSED): per-token argmin + direct output write. Round-6: phase 1
// restructured for MLP -- each bb-iter issues ALL 32 float4 G-fragment loads
// (4 tokens x 8 frags = 16 KB/wave) back-to-back, pinned by sched_barrier(0),
// THEN consumes tokens sequentially. Round-5 proved the compiler won't do
// this on its own (VGPR stayed 64 -> ~6-8 serialized L2 exposures/iter).
// launch_bounds(256,2): 256-reg cap, no spill; occupancy floats ~2-3 w/SIMD.
// EXACTNESS: per-token score chain (s asc, xyzw asc, strict-<), lane->v map,
// and lexicographic 64-lane reduce are VERBATIM -- load order cannot change
// values -> bit-identical bestVs and output.
// ---------------------------------------------------------------------------
__global__ __launch_bounds__(256, 2) void argmin_write_kernel(const int* __restrict__ seq,
                                                              const int* __restrict__ seq2,
                                                              const float* __restrict__ alpha,
                                                              const float* __restrict__ G,
                                                              const float* __restrict__ norms,
                                                              const float* __restrict__ W,
                                                              float* __restrict__ out) {
    __shared__ float T[32][129];   // [tok][d half], stride 129 -> <=2-way banks
    __shared__ int bestVs[32];
    const int tid = threadIdx.x;
    const int wave = tid >> 6;
    const int lane = tid & 63;
    const int t0 = blockIdx.x * 32;       // first token of block

    float4 nn_r[4];
#pragma unroll
    for (int s = 0; s < 4; ++s) nn_r[s] = ((const float4*)norms)[s * 64 + lane];

    const float a = alpha[0];
    const float c0 = -2.0f * (1.0f - a);
    const float c1 = -2.0f * a;

    // ---- Phase 1: argmin for this wave's 8 tokens, 4 at a time -------------
    for (int bb = 0; bb < 2; ++bb) {
        const int base_t = t0 + wave * 8 + bb * 4;   // global token of q=0
        const int base_l = wave * 8 + bb * 4;        // block-local
        int iv[4], jv[4];
#pragma unroll
        for (int q = 0; q < 4; ++q) { iv[q] = seq[base_t + q]; jv[q] = seq2[base_t + q]; }

        // issue ALL 32 fragment loads (16 KB/wave in flight), then pin.
        float4 gi[4][4], gj[4][4];
#pragma unroll
        for (int q = 0; q < 4; ++q) {
            const float4* Gi = (const float4*)(G + iv[q] * Vn);
            const float4* Gj = (const float4*)(G + jv[q] * Vn);
#pragma unroll
            for (int s = 0; s < 4; ++s) {
                const int e = s * 64 + lane;
                gi[q][s] = Gi[e];
                gj[q][s] = Gj[e];
            }
        }
        __builtin_amdgcn_sched_barrier(0);   // loads stay above compute

#pragma unroll
        for (int q = 0; q < 4; ++q) {
            float best = __builtin_inff();
            int vbest = 0;
#pragma unroll
            for (int s = 0; s < 4; ++s) {
                const float4 gjq = gj[q][s];
                const float4 giq = gi[q][s];
                const float4 nn = nn_r[s];
                const int v = (s * 64 + lane) * 4;
                const float s0 = fmaf(c1, gjq.x, fmaf(c0, giq.x, nn.x));
                const float s1 = fmaf(c1, gjq.y, fmaf(c0, giq.y, nn.y));
                const float s2 = fmaf(c1, gjq.z, fmaf(c0, giq.z, nn.z));
                const float s3 = fmaf(c1, gjq.w, fmaf(c0, giq.w, nn.w));
                if (s0 < best) { best = s0; vbest = v; }
                if (s1 < best) { best = s1; vbest = v + 1; }
                if (s2 < best) { best = s2; vbest = v + 2; }
                if (s3 < best) { best = s3; vbest = v + 3; }
            }
            // 64-lane reduce, lexicographic (score, v) = jnp.argmin first-min
#pragma unroll
            for (int off = 32; off >= 1; off >>= 1) {
                const float ob = __shfl_down(best, off, 64);
                const int   vb = __shfl_down(vbest, off, 64);
                if (ob < best || (ob == best && vb < vbest)) { best = ob; vbest = vb; }
            }
            if (lane == 0) bestVs[base_l + q] = vbest;
        }
    }
    __syncthreads();

    // ---- Phase 2: two d-halves of 128; T[32][129] --------------------------
    const int b   = t0 >> 8;
    const int hw0 = t0 & 255;
    float* outb = out + b * 65536 + hw0;
    const int tok = tid >> 3;        // 0..31 (gather mapping)
    const int l8  = tid & 7;
    const int hw4  = (tid & 7) * 4;  // 0..28 (write mapping)
    const int drow = tid >> 3;       // 0..31
#pragma unroll
    for (int half = 0; half < 2; ++half) {
        const int v = bestVs[tok];
        const float4* Wr = (const float4*)(W + v * Dn + half * 128);
#pragma unroll
        for (int p = 0; p < 4; ++p) {
            const int d4 = p * 8 + l8;          // local float4 idx, 0..31
            const float4 w4 = Wr[d4];
            T[tok][d4 * 4 + 0] = w4.x;
            T[tok][d4 * 4 + 1] = w4.y;
            T[tok][d4 * 4 + 2] = w4.z;
            T[tok][d4 * 4 + 3] = w4.w;
        }
        __syncthreads();
#pragma unroll
        for (int dp = 0; dp < 128; dp += 32) {
            const int dl = dp + drow;           // local d, 0..127
            const int d = half * 128 + dl;
            vfloat4 o;
            o.x = T[hw4 + 0][dl];
            o.y = T[hw4 + 1][dl];
            o.z = T[hw4 + 2][dl];
            o.w = T[hw4 + 3][dl];
            __builtin_nontemporal_store(o, (vfloat4*)(outb + d * 256 + hw4));
        }
        __syncthreads();
    }
}

// ---------------------------------------------------------------------------
extern "C" void kernel_launch(void* const* d_in, const int* in_sizes, int n_in,
                              void* d_out, int out_size, void* d_ws, size_t ws_size,
                              hipStream_t stream) {
    const int*   seq   = (const int*)d_in[0];    // [256,256] int32
    const int*   seq2  = (const int*)d_in[1];    // [256,256] int32
    const float* alpha = (const float*)d_in[2];  // [1]
    const float* W     = (const float*)d_in[3];  // [1024,256] f32
    float* out = (float*)d_out;                  // [256,256,16,16] f32

    char* ws = (char*)d_ws;
    float* G     = (float*)(ws);             // 4 MB
    float* norms = (float*)(ws + 4194304);   // 4 KB

    gram_kernel<<<dim3(32, 16), 256, 0, stream>>>(W, G, norms);
    argmin_write_kernel<<<NT / 32, 256, 0, stream>>>(seq, seq2, alpha, G, norms, W, out);
}

// Round 7
// 128.432 us; speedup vs baseline: 1.0542x; 1.0542x over previous
//
#include <hip/hip_runtime.h>

static constexpr int Vn = 1024;   // codebook size
static constexpr int Dn = 256;    // code dim
static constexpr int NT = 65536;  // B * TOK

typedef float vfloat4 __attribute__((ext_vector_type(4)));  // native vec for stores

// ---------------------------------------------------------------------------
// Kernel 1: G = W * W^T (1024x1024, K=256), fp32. VERBATIM round-4 (best
// measured). nt G stores -> clean copies in L3 for all XCDs to pull.
// fmaf chain k=0..255 ascending -> bit-identical G/norms.
// ---------------------------------------------------------------------------
__global__ __launch_bounds__(256) void gram_kernel(const float* __restrict__ W,
                                                   float* __restrict__ G,
                                                   float* __restrict__ norms) {
    __shared__ float As[32][68];   // [k-in-chunk][m 0..63], 16B-aligned rows
    __shared__ float Bs[32][36];   // [k-in-chunk][n 0..31], 144B rows
    const int tid = threadIdx.x;
    const int tx = tid & 7;        // 0..7  -> 4 consecutive cols
    const int ty = tid >> 3;       // 0..31 -> 2 consecutive rows
    const int bm = blockIdx.y * 64;
    const int bn = blockIdx.x * 32;
    const float4* Wv = (const float4*)W;   // [1024][64] float4

    const int m0  = tid >> 3;      // 0..31
    const int kql = tid & 7;       // f4 within the 32-k chunk

    float4 pa[2], pb;
#pragma unroll
    for (int s = 0; s < 2; ++s)
        pa[s] = Wv[(bm + m0 + 32 * s) * 64 + kql];
    pb = Wv[(bn + m0) * 64 + kql];

    float acc[2][4] = {};
    for (int c = 0; c < 8; ++c) {
#pragma unroll
        for (int s = 0; s < 2; ++s) {
            const int m = m0 + 32 * s;
            As[kql * 4 + 0][m] = pa[s].x;
            As[kql * 4 + 1][m] = pa[s].y;
            As[kql * 4 + 2][m] = pa[s].z;
            As[kql * 4 + 3][m] = pa[s].w;
        }
        Bs[kql * 4 + 0][m0] = pb.x;
        Bs[kql * 4 + 1][m0] = pb.y;
        Bs[kql * 4 + 2][m0] = pb.z;
        Bs[kql * 4 + 3][m0] = pb.w;
        __syncthreads();
        if (c < 7) {
            const int kq = (c + 1) * 8 + kql;
#pragma unroll
            for (int s = 0; s < 2; ++s)
                pa[s] = Wv[(bm + m0 + 32 * s) * 64 + kq];
            pb = Wv[(bn + m0) * 64 + kq];
        }
        const float* Ab = &As[0][ty * 2];
        const float* Bb = &Bs[0][tx * 4];
        float2 a_c = *(const float2*)Ab;
        float4 b_c = *(const float4*)Bb;
#pragma unroll
        for (int kk = 0; kk < 32; ++kk) {
            const int kn = (kk < 31) ? kk + 1 : kk;
            const float2 a_n = *(const float2*)(Ab + kn * 68);
            const float4 b_n = *(const float4*)(Bb + kn * 36);
            const float a_s[2] = {a_c.x, a_c.y};
            const float b_s[4] = {b_c.x, b_c.y, b_c.z, b_c.w};
#pragma unroll
            for (int u = 0; u < 2; ++u)
#pragma unroll
                for (int w = 0; w < 4; ++w)
                    acc[u][w] = fmaf(a_s[u], b_s[w], acc[u][w]);  // k ascending
            a_c = a_n;
            b_c = b_n;
        }
        __syncthreads();
    }
#pragma unroll
    for (int u = 0; u < 2; ++u) {
        const int row = bm + ty * 2 + u;
        vfloat4 o;
        o.x = acc[u][0]; o.y = acc[u][1]; o.z = acc[u][2]; o.w = acc[u][3];
        __builtin_nontemporal_store(o, (vfloat4*)(G + row * Vn + bn + tx * 4));
        const int cd = row - (bn + tx * 4);
        if (cd >= 0 && cd < 4) norms[row] = acc[u][cd];
    }
}

// ---------------------------------------------------------------------------
// Kernel 2 (SPLIT, round-7): phase-1 argmin ONLY. Writes 1 int/token (256 KB
// total) -- removes the 65 MB output stream that was churning G out of the
// 4 MB/XCD L2s during the gathers (round-6 FETCH=61.5 MB vs 5.5 MB working
// set = 15x G refetch; that far-memory latency was the invariant ~55 us).
// With no concurrent write stream, G warms into each XCD L2 and stays.
// Low VGPR (~64) -> 8 waves/SIMD to hide the now-L2-local latency.
// EXACTNESS: pair body verbatim round-0/2/4 (same lane->v map, same fmaf
// nesting, strict-< orders, lexicographic reduce) -> bit-identical bestV.
// ---------------------------------------------------------------------------
__global__ __launch_bounds__(256) void argmin_kernel(const int* __restrict__ seq,
                                                     const int* __restrict__ seq2,
                                                     const float* __restrict__ alpha,
                                                     const float* __restrict__ G,
                                                     const float* __restrict__ norms,
                                                     int* __restrict__ bestV) {
    const int tid  = threadIdx.x;
    const int wave = tid >> 6;
    const int lane = tid & 63;
    const int t0   = blockIdx.x * 32;     // 32 tokens per block

    float4 nn_r[4];
#pragma unroll
    for (int s = 0; s < 4; ++s) nn_r[s] = ((const float4*)norms)[s * 64 + lane];

    const float a  = alpha[0];
    const float c0 = -2.0f * (1.0f - a);
    const float c1 = -2.0f * a;

    for (int bb = 0; bb < 2; ++bb) {
        const int base_t = t0 + wave * 8 + bb * 4;   // global token of q=0
        int iv[4], jv[4];
#pragma unroll
        for (int q = 0; q < 4; ++q) { iv[q] = seq[base_t + q]; jv[q] = seq2[base_t + q]; }
#pragma unroll
        for (int pair = 0; pair < 2; ++pair) {
            const int qa = pair * 2, qb = pair * 2 + 1;
            const float4* GiA = (const float4*)(G + iv[qa] * Vn);
            const float4* GjA = (const float4*)(G + jv[qa] * Vn);
            const float4* GiB = (const float4*)(G + iv[qb] * Vn);
            const float4* GjB = (const float4*)(G + jv[qb] * Vn);
            float4 gia[4], gja[4], gib[4], gjb[4];
#pragma unroll
            for (int s = 0; s < 4; ++s) {
                const int e = s * 64 + lane;
                gia[s] = GiA[e];
                gja[s] = GjA[e];
                gib[s] = GiB[e];
                gjb[s] = GjB[e];
            }
            float bestA = __builtin_inff(), bestB = __builtin_inff();
            int vA = 0, vB = 0;
#pragma unroll
            for (int s = 0; s < 4; ++s) {
                const int e = s * 64 + lane;  // v = 4e..4e+3 ascending per lane
                const float4 nn = nn_r[s];
                const int v = e * 4;
                {
                    const float s0 = fmaf(c1, gja[s].x, fmaf(c0, gia[s].x, nn.x));
                    const float s1 = fmaf(c1, gja[s].y, fmaf(c0, gia[s].y, nn.y));
                    const float s2 = fmaf(c1, gja[s].z, fmaf(c0, gia[s].z, nn.z));
                    const float s3 = fmaf(c1, gja[s].w, fmaf(c0, gia[s].w, nn.w));
                    if (s0 < bestA) { bestA = s0; vA = v; }
                    if (s1 < bestA) { bestA = s1; vA = v + 1; }
                    if (s2 < bestA) { bestA = s2; vA = v + 2; }
                    if (s3 < bestA) { bestA = s3; vA = v + 3; }
                }
                {
                    const float s0 = fmaf(c1, gjb[s].x, fmaf(c0, gib[s].x, nn.x));
                    const float s1 = fmaf(c1, gjb[s].y, fmaf(c0, gib[s].y, nn.y));
                    const float s2 = fmaf(c1, gjb[s].z, fmaf(c0, gib[s].z, nn.z));
                    const float s3 = fmaf(c1, gjb[s].w, fmaf(c0, gib[s].w, nn.w));
                    if (s0 < bestB) { bestB = s0; vB = v; }
                    if (s1 < bestB) { bestB = s1; vB = v + 1; }
                    if (s2 < bestB) { bestB = s2; vB = v + 2; }
                    if (s3 < bestB) { bestB = s3; vB = v + 3; }
                }
            }
#pragma unroll
            for (int off = 32; off >= 1; off >>= 1) {
                const float oa = __shfl_down(bestA, off, 64);
                const int   va = __shfl_down(vA, off, 64);
                if (oa < bestA || (oa == bestA && va < vA)) { bestA = oa; vA = va; }
                const float ob = __shfl_down(bestB, off, 64);
                const int   vb = __shfl_down(vB, off, 64);
                if (ob < bestB || (ob == bestB && vb < vB)) { bestB = ob; vB = vb; }
            }
            if (lane == 0) {
                bestV[base_t + qa] = vA;
                bestV[base_t + qb] = vB;
            }
        }
    }
}

// ---------------------------------------------------------------------------
// Kernel 3: output writer. VERBATIM round-3 (passed bit-exact): block = 32
// consecutive tokens, LDS transpose, 128 B nt store lines. Pure stream.
// ---------------------------------------------------------------------------
__global__ __launch_bounds__(256) void write_kernel(const int* __restrict__ bestV,
                                                    const float* __restrict__ W,
                                                    float* __restrict__ out) {
    __shared__ float T[32][129];
    const int tid = threadIdx.x;
    const int t0  = blockIdx.x * 32;
    const int b   = t0 >> 8;
    const int hw0 = t0 & 255;
    float* outb = out + b * 65536 + hw0;
    const int tok  = tid >> 3;
    const int l8   = tid & 7;
    const int hw4  = (tid & 7) * 4;
    const int drow = tid >> 3;
    const int v = bestV[t0 + tok];        // 8 lanes/token broadcast
#pragma unroll
    for (int half = 0; half < 2; ++half) {
        const float4* Wr = (const float4*)(W + v * Dn + half * 128);
#pragma unroll
        for (int p = 0; p < 4; ++p) {
            const int d4 = p * 8 + l8;
            const float4 w4 = Wr[d4];
            T[tok][d4 * 4 + 0] = w4.x;
            T[tok][d4 * 4 + 1] = w4.y;
            T[tok][d4 * 4 + 2] = w4.z;
            T[tok][d4 * 4 + 3] = w4.w;
        }
        __syncthreads();
#pragma unroll
        for (int dp = 0; dp < 128; dp += 32) {
            const int dl = dp + drow;
            const int d = half * 128 + dl;
            vfloat4 o;
            o.x = T[hw4 + 0][dl];
            o.y = T[hw4 + 1][dl];
            o.z = T[hw4 + 2][dl];
            o.w = T[hw4 + 3][dl];
            __builtin_nontemporal_store(o, (vfloat4*)(outb + d * 256 + hw4));
        }
        __syncthreads();
    }
}

// ---------------------------------------------------------------------------
extern "C" void kernel_launch(void* const* d_in, const int* in_sizes, int n_in,
                              void* d_out, int out_size, void* d_ws, size_t ws_size,
                              hipStream_t stream) {
    const int*   seq   = (const int*)d_in[0];    // [256,256] int32
    const int*   seq2  = (const int*)d_in[1];    // [256,256] int32
    const float* alpha = (const float*)d_in[2];  // [1]
    const float* W     = (const float*)d_in[3];  // [1024,256] f32
    float* out = (float*)d_out;                  // [256,256,16,16] f32

    char* ws = (char*)d_ws;
    float* G     = (float*)(ws);                       // 4 MB
    float* norms = (float*)(ws + 4194304);             // 4 KB
    int*   bestV = (int*)(ws + 4194304 + 4096);        // 256 KB

    gram_kernel<<<dim3(32, 16), 256, 0, stream>>>(W, G, norms);
    argmin_kernel<<<NT / 32, 256, 0, stream>>>(seq, seq2, alpha, G, norms, bestV);
    write_kernel<<<NT / 32, 256, 0, stream>>>(bestV, W, out);
}

// Round 8
// 128.403 us; speedup vs baseline: 1.0544x; 1.0002x over previous
//
#include <hip/hip_runtime.h>

static constexpr int Vn = 1024;   // codebook size
static constexpr int Dn = 256;    // code dim
static constexpr int NT = 65536;  // B * TOK

typedef float vfloat4 __attribute__((ext_vector_type(4)));  // native vec for stores

// ---------------------------------------------------------------------------
// Kernel 1 (round-8): SYMMETRIC gram. G = W*W^T is symmetric and IEEE mul
// commutes (fmaf(a,b,c) == fmaf(b,a,c) bitwise), so we compute only the 528
// upper-triangle 32x32 tiles and transpose-store the mirror -- bit-identical
// G/norms to all passing rounds at half the FMA and half the LDS traffic.
// 1-wave blocks (64 thr), 4x4 outputs/thread: per kk 2x ds_read_b128
// (a4: 8 addrs, stride-4 banks, 8-lane bcast; b4 same -> conflict-free)
// for 16 FMA = 1.5 cy LDS/FMA. 528 blocks ~= 2/CU; single-wave barriers
// are near-free. fmaf chain k=0..255 strictly ascending from 0.0f.
// ---------------------------------------------------------------------------
__global__ __launch_bounds__(64) void gram_sym_kernel(const float* __restrict__ W,
                                                      float* __restrict__ G,
                                                      float* __restrict__ norms) {
    __shared__ float As[32][36];   // [k-in-chunk][m], 144 B rows (16B-aligned)
    __shared__ float Bs[32][36];
    const int tid = threadIdx.x;   // 0..63

    // decode linear block id -> upper-tri tile (ti <= tj), row-major
    int L = blockIdx.x, ti = 0;
    while (L >= 32 - ti) { L -= 32 - ti; ++ti; }
    const int tj = ti + L;
    const int bm = ti * 32;
    const int bn = tj * 32;
    const float4* Wv = (const float4*)W;   // [1024][64] float4

    const int m0  = tid >> 3;      // 0..7 (+8s for s=0..3)
    const int kql = tid & 7;       // f4 within the 32-k chunk
    const int tx  = tid & 7;       // 0..7 -> 4 consecutive cols
    const int ty  = tid >> 3;      // 0..7 -> 4 consecutive rows

    float4 pa[4], pb[4];
#pragma unroll
    for (int s = 0; s < 4; ++s) {  // prologue: chunk 0 (8 lanes/row, 128B/row)
        pa[s] = Wv[(bm + m0 + 8 * s) * 64 + kql];
        pb[s] = Wv[(bn + m0 + 8 * s) * 64 + kql];
    }

    float acc[4][4] = {};
    for (int c = 0; c < 8; ++c) {
        // regs -> LDS, transposed to [k][m]
#pragma unroll
        for (int s = 0; s < 4; ++s) {
            const int m = m0 + 8 * s;
            As[kql * 4 + 0][m] = pa[s].x;
            As[kql * 4 + 1][m] = pa[s].y;
            As[kql * 4 + 2][m] = pa[s].z;
            As[kql * 4 + 3][m] = pa[s].w;
            Bs[kql * 4 + 0][m] = pb[s].x;
            Bs[kql * 4 + 1][m] = pb[s].y;
            Bs[kql * 4 + 2][m] = pb[s].z;
            Bs[kql * 4 + 3][m] = pb[s].w;
        }
        __syncthreads();
        if (c < 7) {               // prefetch chunk c+1 under the compute below
            const int kq = (c + 1) * 8 + kql;
#pragma unroll
            for (int s = 0; s < 4; ++s) {
                pa[s] = Wv[(bm + m0 + 8 * s) * 64 + kq];
                pb[s] = Wv[(bn + m0 + 8 * s) * 64 + kq];
            }
        }
        // inner: 2 x ds_read_b128 + 16 FMA per kk, register double-buffered
        const float* Ab = &As[0][ty * 4];
        const float* Bb = &Bs[0][tx * 4];
        float4 a_c = *(const float4*)Ab;
        float4 b_c = *(const float4*)Bb;
#pragma unroll
        for (int kk = 0; kk < 32; ++kk) {
            const int kn = (kk < 31) ? kk + 1 : kk;       // clamped prefetch
            const float4 a_n = *(const float4*)(Ab + kn * 36);
            const float4 b_n = *(const float4*)(Bb + kn * 36);
            const float a_s[4] = {a_c.x, a_c.y, a_c.z, a_c.w};
            const float b_s[4] = {b_c.x, b_c.y, b_c.z, b_c.w};
#pragma unroll
            for (int u = 0; u < 4; ++u)
#pragma unroll
                for (int w = 0; w < 4; ++w)
                    acc[u][w] = fmaf(a_s[u], b_s[w], acc[u][w]);  // k ascending
            a_c = a_n;
            b_c = b_n;
        }
        __syncthreads();
    }
    // epilogue: direct tile store + (off-diag) transpose mirror store.
    // Mirror is bit-identical to computing G[c][r] directly (mul commutes).
#pragma unroll
    for (int u = 0; u < 4; ++u) {
        const int row = bm + ty * 4 + u;
        vfloat4 o;
        o.x = acc[u][0]; o.y = acc[u][1]; o.z = acc[u][2]; o.w = acc[u][3];
        __builtin_nontemporal_store(o, (vfloat4*)(G + row * Vn + bn + tx * 4));
    }
    if (ti != tj) {
#pragma unroll
        for (int w = 0; w < 4; ++w) {
            const int col = bn + tx * 4 + w;
            vfloat4 o;
            o.x = acc[0][w]; o.y = acc[1][w]; o.z = acc[2][w]; o.w = acc[3][w];
            __builtin_nontemporal_store(o, (vfloat4*)(G + col * Vn + bm + ty * 4));
        }
    } else if (tx == ty) {
#pragma unroll
        for (int u = 0; u < 4; ++u) norms[bm + ty * 4 + u] = acc[u][u];
    }
}

// ---------------------------------------------------------------------------
// Kernel 2: phase-1 argmin ONLY. VERBATIM round-7 (passing): 256 KB bestV
// output, no 65 MB write stream churning G out of the XCD L2s.
// EXACTNESS: pair body verbatim (lane->v map, fmaf nesting, strict-< orders,
// lexicographic reduce) -> bit-identical bestV.
// ---------------------------------------------------------------------------
__global__ __launch_bounds__(256) void argmin_kernel(const int* __restrict__ seq,
                                                     const int* __restrict__ seq2,
                                                     const float* __restrict__ alpha,
                                                     const float* __restrict__ G,
                                                     const float* __restrict__ norms,
                                                     int* __restrict__ bestV) {
    const int tid  = threadIdx.x;
    const int wave = tid >> 6;
    const int lane = tid & 63;
    const int t0   = blockIdx.x * 32;     // 32 tokens per block

    float4 nn_r[4];
#pragma unroll
    for (int s = 0; s < 4; ++s) nn_r[s] = ((const float4*)norms)[s * 64 + lane];

    const float a  = alpha[0];
    const float c0 = -2.0f * (1.0f - a);
    const float c1 = -2.0f * a;

    for (int bb = 0; bb < 2; ++bb) {
        const int base_t = t0 + wave * 8 + bb * 4;   // global token of q=0
        int iv[4], jv[4];
#pragma unroll
        for (int q = 0; q < 4; ++q) { iv[q] = seq[base_t + q]; jv[q] = seq2[base_t + q]; }
#pragma unroll
        for (int pair = 0; pair < 2; ++pair) {
            const int qa = pair * 2, qb = pair * 2 + 1;
            const float4* GiA = (const float4*)(G + iv[qa] * Vn);
            const float4* GjA = (const float4*)(G + jv[qa] * Vn);
            const float4* GiB = (const float4*)(G + iv[qb] * Vn);
            const float4* GjB = (const float4*)(G + jv[qb] * Vn);
            float4 gia[4], gja[4], gib[4], gjb[4];
#pragma unroll
            for (int s = 0; s < 4; ++s) {
                const int e = s * 64 + lane;
                gia[s] = GiA[e];
                gja[s] = GjA[e];
                gib[s] = GiB[e];
                gjb[s] = GjB[e];
            }
            float bestA = __builtin_inff(), bestB = __builtin_inff();
            int vA = 0, vB = 0;
#pragma unroll
            for (int s = 0; s < 4; ++s) {
                const int e = s * 64 + lane;  // v = 4e..4e+3 ascending per lane
                const float4 nn = nn_r[s];
                const int v = e * 4;
                {
                    const float s0 = fmaf(c1, gja[s].x, fmaf(c0, gia[s].x, nn.x));
                    const float s1 = fmaf(c1, gja[s].y, fmaf(c0, gia[s].y, nn.y));
                    const float s2 = fmaf(c1, gja[s].z, fmaf(c0, gia[s].z, nn.z));
                    const float s3 = fmaf(c1, gja[s].w, fmaf(c0, gia[s].w, nn.w));
                    if (s0 < bestA) { bestA = s0; vA = v; }
                    if (s1 < bestA) { bestA = s1; vA = v + 1; }
                    if (s2 < bestA) { bestA = s2; vA = v + 2; }
                    if (s3 < bestA) { bestA = s3; vA = v + 3; }
                }
                {
                    const float s0 = fmaf(c1, gjb[s].x, fmaf(c0, gib[s].x, nn.x));
                    const float s1 = fmaf(c1, gjb[s].y, fmaf(c0, gib[s].y, nn.y));
                    const float s2 = fmaf(c1, gjb[s].z, fmaf(c0, gib[s].z, nn.z));
                    const float s3 = fmaf(c1, gjb[s].w, fmaf(c0, gib[s].w, nn.w));
                    if (s0 < bestB) { bestB = s0; vB = v; }
                    if (s1 < bestB) { bestB = s1; vB = v + 1; }
                    if (s2 < bestB) { bestB = s2; vB = v + 2; }
                    if (s3 < bestB) { bestB = s3; vB = v + 3; }
                }
            }
#pragma unroll
            for (int off = 32; off >= 1; off >>= 1) {
                const float oa = __shfl_down(bestA, off, 64);
                const int   va = __shfl_down(vA, off, 64);
                if (oa < bestA || (oa == bestA && va < vA)) { bestA = oa; vA = va; }
                const float ob = __shfl_down(bestB, off, 64);
                const int   vb = __shfl_down(vB, off, 64);
                if (ob < bestB || (ob == bestB && vb < vB)) { bestB = ob; vB = vb; }
            }
            if (lane == 0) {
                bestV[base_t + qa] = vA;
                bestV[base_t + qb] = vB;
            }
        }
    }
}

// ---------------------------------------------------------------------------
// Kernel 3: output writer. VERBATIM round-3/7 (passing): block = 32
// consecutive tokens, LDS transpose, 128 B nt store lines. Pure stream.
// ---------------------------------------------------------------------------
__global__ __launch_bounds__(256) void write_kernel(const int* __restrict__ bestV,
                                                    const float* __restrict__ W,
                                                    float* __restrict__ out) {
    __shared__ float T[32][129];
    const int tid = threadIdx.x;
    const int t0  = blockIdx.x * 32;
    const int b   = t0 >> 8;
    const int hw0 = t0 & 255;
    float* outb = out + b * 65536 + hw0;
    const int tok  = tid >> 3;
    const int l8   = tid & 7;
    const int hw4  = (tid & 7) * 4;
    const int drow = tid >> 3;
    const int v = bestV[t0 + tok];        // 8 lanes/token broadcast
#pragma unroll
    for (int half = 0; half < 2; ++half) {
        const float4* Wr = (const float4*)(W + v * Dn + half * 128);
#pragma unroll
        for (int p = 0; p < 4; ++p) {
            const int d4 = p * 8 + l8;
            const float4 w4 = Wr[d4];
            T[tok][d4 * 4 + 0] = w4.x;
            T[tok][d4 * 4 + 1] = w4.y;
            T[tok][d4 * 4 + 2] = w4.z;
            T[tok][d4 * 4 + 3] = w4.w;
        }
        __syncthreads();
#pragma unroll
        for (int dp = 0; dp < 128; dp += 32) {
            const int dl = dp + drow;
            const int d = half * 128 + dl;
            vfloat4 o;
            o.x = T[hw4 + 0][dl];
            o.y = T[hw4 + 1][dl];
            o.z = T[hw4 + 2][dl];
            o.w = T[hw4 + 3][dl];
            __builtin_nontemporal_store(o, (vfloat4*)(outb + d * 256 + hw4));
        }
        __syncthreads();
    }
}

// ---------------------------------------------------------------------------
extern "C" void kernel_launch(void* const* d_in, const int* in_sizes, int n_in,
                              void* d_out, int out_size, void* d_ws, size_t ws_size,
                              hipStream_t stream) {
    const int*   seq   = (const int*)d_in[0];    // [256,256] int32
    const int*   seq2  = (const int*)d_in[1];    // [256,256] int32
    const float* alpha = (const float*)d_in[2];  // [1]
    const float* W     = (const float*)d_in[3];  // [1024,256] f32
    float* out = (float*)d_out;                  // [256,256,16,16] f32

    char* ws = (char*)d_ws;
    float* G     = (float*)(ws);                       // 4 MB
    float* norms = (float*)(ws + 4194304);             // 4 KB
    int*   bestV = (int*)(ws + 4194304 + 4096);        // 256 KB

    gram_sym_kernel<<<528, 64, 0, stream>>>(W, G, norms);
    argmin_kernel<<<NT / 32, 256, 0, stream>>>(seq, seq2, alpha, G, norms, bestV);
    write_kernel<<<NT / 32, 256, 0, stream>>>(bestV, W, out);
}